// Round 6
// baseline (55.130 us; speedup 1.0000x reference)
//
#include <hip/hip_runtime.h>
#include <hip/hip_bf16.h>

#define BB 4
#define TT 2048
#define CC 1024
#define HH 64
#define LOG2E 1.4426950408889634f
#define QSCALE (0.125f * LOG2E)

typedef __attribute__((ext_vector_type(8))) unsigned short ushort8;
typedef __attribute__((ext_vector_type(4))) unsigned short ushort4v;
typedef __attribute__((ext_vector_type(8))) __bf16 bf16x8;
typedef __attribute__((ext_vector_type(4))) float float4v;

static __device__ __forceinline__ unsigned short f2bf(float f) {
    return __builtin_bit_cast(unsigned short, (__bf16)f);  // RNE, hw cvt
}

static __device__ __forceinline__ float4v mfma16(ushort8 a, ushort8 b, float4v c) {
    return __builtin_amdgcn_mfma_f32_16x16x32_bf16(
        __builtin_bit_cast(bf16x8, a), __builtin_bit_cast(bf16x8, b), c, 0, 0, 0);
}

static __device__ __forceinline__ ushort8 cvt8(float4v a, float4v b) {
    ushort8 r;
#pragma unroll
    for (int i = 0; i < 4; ++i) { r[i] = f2bf(a[i]); r[4 + i] = f2bf(b[i]); }
    return r;
}

// raw barrier: publish LDS writes (lgkmcnt) WITHOUT draining vmcnt —
// keeps the register-staged global prefetch pipeline alive across steps.
#define BARRIER()                                            \
    do {                                                     \
        asm volatile("s_waitcnt lgkmcnt(0)" ::: "memory");   \
        __builtin_amdgcn_s_barrier();                        \
        asm volatile("" ::: "memory");                       \
    } while (0)

// ---------------------------------------------------------------------------
// Kernel 0: pack W (f32 [C][64] x3) into MFMA-B-fragment-interleaved bf16.
// unit U = ((kc*2 + ks)*12 + nt)*64 + lane, 8 bf16/unit:
//   value[j] = W_y[kc*64 + ks*32 + 8*(lane>>4) + j][16*(nt&3) + (lane&15)]
// Softmax scale (1/8 * log2e) folded into Wq here. Grid 96 = 16 kc x 6 parts;
// W staged TRANSPOSED+padded in LDS so the gather is 2x b128 per unit.
// ---------------------------------------------------------------------------
__global__ __launch_bounds__(256) void wconv_kernel(
    const float* __restrict__ Wq, const float* __restrict__ Wk,
    const float* __restrict__ Wv, unsigned short* __restrict__ wf)
{
    __shared__ __align__(16) float wsT[3][64][68];   // transposed, pad 64->68
    const int kc = blockIdx.x / 6, part = blockIdx.x % 6;
    const int t = threadIdx.x;
    const int r = t >> 2, c0 = (t & 3) << 4;
    const float* Ws[3] = {Wq, Wk, Wv};
#pragma unroll
    for (int y = 0; y < 3; ++y) {
        const float* src = Ws[y] + (size_t)(kc * 64 + r) * HH + c0;
        const float sc = (y == 0) ? QSCALE : 1.0f;
#pragma unroll
        for (int i = 0; i < 16; ++i) wsT[y][c0 + i][r] = src[i] * sc;
    }
    __syncthreads();
    const int U = part * 256 + t;                    // 0..1535
    const int lane = U & 63, qq = U >> 6;
    const int nt = qq % 12, ks = qq / 12;
    const int y = nt >> 2;
    const int col = 16 * (nt & 3) + (lane & 15);
    const int kl = ks * 32 + 8 * (lane >> 4);
    float4v v0 = *(const float4v*)&wsT[y][col][kl];
    float4v v1 = *(const float4v*)&wsT[y][col][kl + 4];
    *(ushort8*)&wf[((size_t)kc * 1536 + U) * 8] = cvt8(v0, v1);
}

// ---------------------------------------------------------------------------
// Kernel 1: fused q/k/v projection. 256 blocks x 12 waves, BM=32, BK=64.
// W STREAMED 2-deep from frag-packed wf (2 coalesced 16B loads/step/wave,
// ~16 VGPR) -- NOT register-resident (R5's 128-VGPR residency forced spills
// at 12 waves/block). x staged through a 4-deep register pipeline:
// issue kc+4, cvt+swizzled ds_write kc+1, raw-barrier (no vmcnt drain).
// v waves swap MFMA operands to emit vT[b][h][t] directly.
// ---------------------------------------------------------------------------
__global__ __launch_bounds__(768) void proj_kernel(
    const float* __restrict__ x, const unsigned short* __restrict__ wf,
    unsigned short* __restrict__ qo, unsigned short* __restrict__ ko,
    unsigned short* __restrict__ vo)
{
    __shared__ __align__(16) unsigned short xa[2][2048];   // 2 x 4KB, 16B units

    const int t0 = blockIdx.x << 5;                        // 32 rows
    const int tid = threadIdx.x;
    const int w = tid >> 6;                                // 0..11 = (y,nf)
    const int lane = tid & 63;
    const int l15 = lane & 15, g = lane >> 4;

    // x staging (threads 0..255): 8 f32 -> one swizzled 16B LDS unit
    const bool stg = tid < 256;
    const int sr = tid >> 3, su = tid & 7;
    const int soff = (sr * 8 + (su ^ (sr & 7))) * 8;
    const float* xp = x + (size_t)(t0 + sr) * CC + su * 8;

    float4v xr[4][2];                                      // 4-deep x pipeline
    if (stg) {
#pragma unroll
        for (int p = 0; p < 4; ++p) {
            xr[p][0] = *(const float4v*)(xp + p * 64);
            xr[p][1] = *(const float4v*)(xp + p * 64 + 4);
        }
    }

    // W stream: frag (kc,ks) at wfp + (kc*2+ks)*6144 (ushorts), 2-deep shadow
    const unsigned short* wfp = wf + ((size_t)w * 64 + lane) * 8;
    ushort8 bc0 = *(const ushort8*)(wfp);
    ushort8 bc1 = *(const ushort8*)(wfp + 6144);
    ushort8 bn0 = *(const ushort8*)(wfp + 2 * 6144);
    ushort8 bn1 = *(const ushort8*)(wfp + 3 * 6144);

    if (stg) *(ushort8*)&xa[0][soff] = cvt8(xr[0][0], xr[0][1]);
    BARRIER();

    // swizzled A-frag read offsets
    const int sw = l15 & 7;
    const int r00 = (l15 * 8 + (g ^ sw)) * 8;
    const int r01 = (l15 * 8 + ((4 + g) ^ sw)) * 8;
    const int r10 = ((16 + l15) * 8 + (g ^ sw)) * 8;
    const int r11 = ((16 + l15) * 8 + ((4 + g) ^ sw)) * 8;

    float4v ac0 = (float4v)0.0f, ac1 = (float4v)0.0f;

#pragma unroll
    for (int kc = 0; kc < 16; ++kc) {
        const int cur = kc & 1;
        if (stg && kc + 4 < 16) {                          // issue x kc+4
            xr[kc & 3][0] = *(const float4v*)(xp + (kc + 4) * 64);
            xr[kc & 3][1] = *(const float4v*)(xp + (kc + 4) * 64 + 4);
        }
        ushort8 nw0, nw1;
        if (kc + 2 < 16) {                                 // issue W kc+2
            nw0 = *(const ushort8*)(wfp + (size_t)(2 * kc + 4) * 6144);
            nw1 = *(const ushort8*)(wfp + (size_t)(2 * kc + 5) * 6144);
        }
        const unsigned short* xb = xa[cur];
        ushort8 a00 = *(const ushort8*)&xb[r00];
        ushort8 a01 = *(const ushort8*)&xb[r01];
        ushort8 a10 = *(const ushort8*)&xb[r10];
        ushort8 a11 = *(const ushort8*)&xb[r11];
        if (w < 8) {                      // q,k: D = x*W   (row=t, col=h)
            ac0 = mfma16(a00, bc0, ac0);
            ac0 = mfma16(a01, bc1, ac0);
            ac1 = mfma16(a10, bc0, ac1);
            ac1 = mfma16(a11, bc1, ac1);
        } else {                          // v: D = (x*W)^T (row=h, col=t)
            ac0 = mfma16(bc0, a00, ac0);
            ac0 = mfma16(bc1, a01, ac0);
            ac1 = mfma16(bc0, a10, ac1);
            ac1 = mfma16(bc1, a11, ac1);
        }
        if (stg && kc + 1 < 16)                            // stage x kc+1
            *(ushort8*)&xa[cur ^ 1][soff] =
                cvt8(xr[(kc + 1) & 3][0], xr[(kc + 1) & 3][1]);
        BARRIER();
        bc0 = bn0; bc1 = bn1;
        if (kc + 2 < 16) { bn0 = nw0; bn1 = nw1; }
    }

    if (w < 8) {
        unsigned short* dst = (w < 4) ? qo : ko;
        const int nf = w & 3;
#pragma unroll
        for (int mt = 0; mt < 2; ++mt) {
            float4v a = mt ? ac1 : ac0;
#pragma unroll
            for (int r = 0; r < 4; ++r)
                dst[(size_t)(t0 + 16 * mt + 4 * g + r) * HH + 16 * nf + l15] =
                    f2bf(a[r]);
        }
    } else {
        const int nf = w - 8;
        const int b = t0 >> 11, tl = t0 & (TT - 1);
#pragma unroll
        for (int mt = 0; mt < 2; ++mt) {
            float4v a = mt ? ac1 : ac0;
#pragma unroll
            for (int r = 0; r < 4; ++r)
                vo[((size_t)b * HH + 16 * nf + 4 * g + r) * TT + tl + 16 * mt + l15] =
                    f2bf(a[r]);
        }
    }
}

// ---------------------------------------------------------------------------
// Kernel 2: causal flash attention, KVBLK=64, 8 waves/block, 16 queries.
// __launch_bounds__(512,2): VGPR cap 256 (demand ~135) -> guaranteed no
// spill. Per-lane l (no sum-shuffles; 4 g-partials summed in LDS merge).
// Swapped QK^T keeps softmax in registers; PV reuses the P register layout
// as B-fragment (kappa trick), V^T gathered to match. Base-2 softmax.
// ---------------------------------------------------------------------------
__global__ __launch_bounds__(512, 2) void attn_kernel(
    const unsigned short* __restrict__ qw,
    const unsigned short* __restrict__ kw,
    const unsigned short* __restrict__ vw,
    float* __restrict__ out)
{
    __shared__ float om[8][16];
    __shared__ float olg[8][4][16];
    __shared__ __align__(16) float oo[8][16][64];

    const int idx = blockIdx.x;
    const int b = idx & (BB - 1);
    const int qt = (TT / 16 - 1) - (idx >> 2);    // heavy tiles first
    const int q0 = qt << 4;
    const int tid = threadIdx.x;
    const int w = tid >> 6;
    const int lane = tid & 63;
    const int l15 = lane & 15;
    const int g = lane >> 4;
    const int q = q0 + l15;

    const unsigned short* qrow = qw + (size_t)(b * TT + q) * HH + 8 * g;
    ushort8 qf0 = *(const ushort8*)qrow;
    ushort8 qf1 = *(const ushort8*)(qrow + 32);

    const unsigned short* kb = kw + (size_t)b * TT * HH;
    const unsigned short* vb = vw + (size_t)b * HH * TT;

    float m_run = -3.0e38f, l_run = 0.0f;
    float4v o[4];
#pragma unroll
    for (int i = 0; i < 4; ++i) o[i] = (float4v)0.0f;

    for (int kv0 = 64 * w; kv0 < q0 + 16; kv0 += 512) {
        const unsigned short* kr = kb + (size_t)(kv0 + l15) * HH + 8 * g;
        ushort8 akl[4], akh[4];
#pragma unroll
        for (int f = 0; f < 4; ++f) {
            akl[f] = *(const ushort8*)(kr + f * 16 * HH);
            akh[f] = *(const ushort8*)(kr + f * 16 * HH + 32);
        }
        ushort8 av[4][2];                 // V^T kappa-packed, issued early
#pragma unroll
        for (int ht = 0; ht < 4; ++ht) {
            const unsigned short* vp = vb + (size_t)(16 * ht + l15) * TT + kv0 + 4 * g;
#pragma unroll
            for (int g2 = 0; g2 < 2; ++g2) {
                ushort4v v0 = *(const ushort4v*)(vp + 32 * g2);
                ushort4v v1 = *(const ushort4v*)(vp + 32 * g2 + 16);
#pragma unroll
                for (int r = 0; r < 4; ++r) {
                    av[ht][g2][r] = v0[r];
                    av[ht][g2][4 + r] = v1[r];
                }
            }
        }

        float4v s[4];  // S^T: lane=q, key = kv0 + 16f + 4g + r
#pragma unroll
        for (int f = 0; f < 4; ++f) {
            s[f] = mfma16(akl[f], qf0, (float4v)0.0f);
            s[f] = mfma16(akh[f], qf1, s[f]);
        }

        if (kv0 + 63 > q0) {  // causal mask on boundary chunks
#pragma unroll
            for (int f = 0; f < 4; ++f)
#pragma unroll
                for (int r = 0; r < 4; ++r)
                    if (kv0 + 16 * f + 4 * g + r > q) s[f][r] = -1e30f;
        }

        float mt = s[0][0];
#pragma unroll
        for (int f = 0; f < 4; ++f)
#pragma unroll
            for (int r = 0; r < 4; ++r) mt = fmaxf(mt, s[f][r]);
        mt = fmaxf(mt, __shfl_xor(mt, 16, 64));
        mt = fmaxf(mt, __shfl_xor(mt, 32, 64));

        const float m_new = fmaxf(m_run, mt);
        const float scale = exp2f(m_run - m_new);
        float sum = 0.0f;                 // per-lane partial (merged via LDS)
#pragma unroll
        for (int f = 0; f < 4; ++f)
#pragma unroll
            for (int r = 0; r < 4; ++r) {
                s[f][r] = exp2f(s[f][r] - m_new);
                sum += s[f][r];
            }
        l_run = l_run * scale + sum;
        m_run = m_new;
#pragma unroll
        for (int i = 0; i < 4; ++i) o[i] *= scale;

        ushort8 bp[2];                    // kappa(g,j) per 32-key group
#pragma unroll
        for (int r = 0; r < 4; ++r) {
            bp[0][r] = f2bf(s[0][r]); bp[0][4 + r] = f2bf(s[1][r]);
            bp[1][r] = f2bf(s[2][r]); bp[1][4 + r] = f2bf(s[3][r]);
        }
#pragma unroll
        for (int ht = 0; ht < 4; ++ht) {
            o[ht] = mfma16(av[ht][0], bp[0], o[ht]);
            o[ht] = mfma16(av[ht][1], bp[1], o[ht]);
        }
    }

    if (lane < 16) om[w][lane] = m_run;
    olg[w][g][l15] = l_run;
#pragma unroll
    for (int ht = 0; ht < 4; ++ht)
        *(float4v*)&oo[w][l15][16 * ht + 4 * g] = o[ht];
    __syncthreads();

#pragma unroll 2
    for (int e = tid; e < 16 * HH; e += 512) {
        const int qq = e >> 6, h = e & 63;
        float mstar = om[0][qq];
#pragma unroll
        for (int w2 = 1; w2 < 8; ++w2) mstar = fmaxf(mstar, om[w2][qq]);
        float lsum = 0.0f, osum = 0.0f;
#pragma unroll
        for (int w2 = 0; w2 < 8; ++w2) {
            const float al = exp2f(om[w2][qq] - mstar);
            const float lw = olg[w2][0][qq] + olg[w2][1][qq] +
                             olg[w2][2][qq] + olg[w2][3][qq];
            lsum += al * lw;
            osum += al * oo[w2][qq][h];
        }
        out[((size_t)b * TT + q0 + qq) * HH + h] = osum / lsum;
    }
}

extern "C" void kernel_launch(void* const* d_in, const int* in_sizes, int n_in,
                              void* d_out, int out_size, void* d_ws, size_t ws_size,
                              hipStream_t stream) {
    // setup_inputs order: x, Wk, Wq, Wv
    const float* x  = (const float*)d_in[0];
    const float* Wk = (const float*)d_in[1];
    const float* Wq = (const float*)d_in[2];
    const float* Wv = (const float*)d_in[3];

    // ws: q bf16 [B*T][64] | k bf16 [B*T][64] | vT bf16 [B][64][T] | wf 384KB
    unsigned short* q_ws  = (unsigned short*)d_ws;
    unsigned short* k_ws  = q_ws + (size_t)BB * TT * HH;
    unsigned short* vt_ws = k_ws + (size_t)BB * TT * HH;
    unsigned short* wf_ws = vt_ws + (size_t)BB * TT * HH;

    wconv_kernel<<<96, 256, 0, stream>>>(Wq, Wk, Wv, wf_ws);
    proj_kernel<<<BB * TT / 32, 768, 0, stream>>>(x, wf_ws, q_ws, k_ws, vt_ws);
    attn_kernel<<<BB * TT / 16, 512, 0, stream>>>(q_ws, k_ws, vt_ws, (float*)d_out);
}

// Round 7
// 50.334 us; speedup vs baseline: 1.0953x; 1.0953x over previous
//
#include <hip/hip_runtime.h>
#include <hip/hip_bf16.h>

#define BB 4
#define TT 2048
#define CC 1024
#define HH 64
#define LOG2E 1.4426950408889634f
#define QSCALE (0.125f * LOG2E)

typedef __attribute__((ext_vector_type(8))) unsigned short ushort8;
typedef __attribute__((ext_vector_type(4))) unsigned short ushort4v;
typedef __attribute__((ext_vector_type(8))) __bf16 bf16x8;
typedef __attribute__((ext_vector_type(4))) float float4v;

static __device__ __forceinline__ unsigned short f2bf(float f) {
    return __builtin_bit_cast(unsigned short, (__bf16)f);  // RNE, hw cvt
}

static __device__ __forceinline__ float4v mfma16(ushort8 a, ushort8 b, float4v c) {
    return __builtin_amdgcn_mfma_f32_16x16x32_bf16(
        __builtin_bit_cast(bf16x8, a), __builtin_bit_cast(bf16x8, b), c, 0, 0, 0);
}

static __device__ __forceinline__ ushort8 cvt8(float4v a, float4v b) {
    ushort8 r;
#pragma unroll
    for (int i = 0; i < 4; ++i) { r[i] = f2bf(a[i]); r[4 + i] = f2bf(b[i]); }
    return r;
}

// raw barrier: publish LDS writes (lgkmcnt) WITHOUT draining vmcnt —
// keeps register-staged global prefetches alive across steps.
#define BARRIER()                                            \
    do {                                                     \
        asm volatile("s_waitcnt lgkmcnt(0)" ::: "memory");   \
        __builtin_amdgcn_s_barrier();                        \
        asm volatile("" ::: "memory");                       \
    } while (0)

// ---------------------------------------------------------------------------
// Kernel 0: pack W (f32 [C][64] x3) into MFMA-B-fragment-interleaved bf16.
// unit U = ((kc*2 + ks)*12 + nt)*64 + lane, 8 bf16/unit:
//   value[j] = W_y[kc*64 + ks*32 + 8*(lane>>4) + j][16*(nt&3) + (lane&15)]
// Softmax scale folded into Wq. 96 blocks = 16 kc x 6 parts.
// ---------------------------------------------------------------------------
__global__ __launch_bounds__(256) void wconv_kernel(
    const float* __restrict__ Wq, const float* __restrict__ Wk,
    const float* __restrict__ Wv, unsigned short* __restrict__ wf)
{
    __shared__ __align__(16) float wsT[3][64][68];   // transposed, pad 64->68
    const int kc = blockIdx.x / 6, part = blockIdx.x % 6;
    const int t = threadIdx.x;
    const int r = t >> 2, c0 = (t & 3) << 4;
    const float* Ws[3] = {Wq, Wk, Wv};
#pragma unroll
    for (int y = 0; y < 3; ++y) {
        const float* src = Ws[y] + (size_t)(kc * 64 + r) * HH + c0;
        const float sc = (y == 0) ? QSCALE : 1.0f;
#pragma unroll
        for (int i = 0; i < 16; ++i) wsT[y][c0 + i][r] = src[i] * sc;
    }
    __syncthreads();
    const int U = part * 256 + t;                    // 0..1535
    const int lane = U & 63, qq = U >> 6;
    const int nt = qq % 12, ks = qq / 12;
    const int y = nt >> 2;
    const int col = 16 * (nt & 3) + (lane & 15);
    const int kl = ks * 32 + 8 * (lane >> 4);
    float4v v0 = *(const float4v*)&wsT[y][col][kl];
    float4v v1 = *(const float4v*)&wsT[y][col][kl + 4];
    *(ushort8*)&wf[((size_t)kc * 1536 + U) * 8] = cvt8(v0, v1);
}

// ---------------------------------------------------------------------------
// Kernel 1: fused q/k/v projection. 512 blocks x 6 waves, BM=16, BK=64.
// 2 blocks/CU for cross-block latency hiding. Wave w owns 2 n-tiles of 12.
// W streamed 2-deep from frag-packed wf; x staged via 4-deep register
// pipeline into swizzled LDS; raw barriers (no vmcnt drain), 1/step.
// v waves swap MFMA operands to emit vT[b][h][t] directly.
// ---------------------------------------------------------------------------
__global__ __launch_bounds__(384) void proj_kernel(
    const float* __restrict__ x, const unsigned short* __restrict__ wf,
    unsigned short* __restrict__ qo, unsigned short* __restrict__ ko,
    unsigned short* __restrict__ vo)
{
    __shared__ __align__(16) unsigned short xa[2][1024];   // 2 x 2KB, 16B units

    const int t0 = blockIdx.x << 4;                        // 16 rows
    const int tid = threadIdx.x;
    const int w = tid >> 6;                                // 0..5
    const int lane = tid & 63;
    const int l15 = lane & 15, g = lane >> 4;
    const int nt0 = 2 * w;                                 // tiles {nt0, nt0+1}

    // x staging (threads 0..127): 8 f32 -> one swizzled 16B LDS unit
    const bool stg = tid < 128;
    const int sr = tid >> 3, su = tid & 7;
    const int soff = (sr * 8 + (su ^ (sr & 7))) * 8;
    const float* xp = x + (size_t)(t0 + sr) * CC + su * 8;

    float4v xr[4][2];                                      // 4-deep x pipeline
    if (stg) {
#pragma unroll
        for (int p = 0; p < 4; ++p) {
            xr[p][0] = *(const float4v*)(xp + p * 64);
            xr[p][1] = *(const float4v*)(xp + p * 64 + 4);
        }
    }

    // W stream: slot s = kc*2+ks at wp + s*6144 (+512 for second tile)
    const unsigned short* wp = wf + ((size_t)nt0 * 64 + lane) * 8;
    ushort8 bc[2][2], bn[2][2];
#pragma unroll
    for (int ks = 0; ks < 2; ++ks)
#pragma unroll
        for (int j = 0; j < 2; ++j) {
            bc[j][ks] = *(const ushort8*)(wp + (size_t)ks * 6144 + j * 512);
            bn[j][ks] = *(const ushort8*)(wp + (size_t)(2 + ks) * 6144 + j * 512);
        }

    if (stg) *(ushort8*)&xa[0][soff] = cvt8(xr[0][0], xr[0][1]);
    BARRIER();

    // swizzled A-frag read offsets
    const int sw = l15 & 7;
    const int r00 = (l15 * 8 + (g ^ sw)) * 8;
    const int r01 = (l15 * 8 + ((4 + g) ^ sw)) * 8;

    float4v acc[2];
    acc[0] = (float4v)0.0f; acc[1] = (float4v)0.0f;

#pragma unroll
    for (int kc = 0; kc < 16; ++kc) {
        const int cur = kc & 1;
        if (stg && kc + 4 < 16) {                          // issue x kc+4
            xr[kc & 3][0] = *(const float4v*)(xp + (kc + 4) * 64);
            xr[kc & 3][1] = *(const float4v*)(xp + (kc + 4) * 64 + 4);
        }
        ushort8 nw[2][2];
        if (kc + 2 < 16) {                                 // issue W kc+2
#pragma unroll
            for (int ks = 0; ks < 2; ++ks)
#pragma unroll
                for (int j = 0; j < 2; ++j)
                    nw[j][ks] = *(const ushort8*)
                        (wp + (size_t)(2 * kc + 4 + ks) * 6144 + j * 512);
        }
        ushort8 a0 = *(const ushort8*)&xa[cur][r00];
        ushort8 a1 = *(const ushort8*)&xa[cur][r01];
        if (w < 4) {                      // q,k: D = x*W   (row=t, col=h)
#pragma unroll
            for (int j = 0; j < 2; ++j) {
                acc[j] = mfma16(a0, bc[j][0], acc[j]);
                acc[j] = mfma16(a1, bc[j][1], acc[j]);
            }
        } else {                          // v: D = (x*W)^T (row=h, col=t)
#pragma unroll
            for (int j = 0; j < 2; ++j) {
                acc[j] = mfma16(bc[j][0], a0, acc[j]);
                acc[j] = mfma16(bc[j][1], a1, acc[j]);
            }
        }
        if (stg && kc + 1 < 16)                            // stage x kc+1
            *(ushort8*)&xa[cur ^ 1][soff] =
                cvt8(xr[(kc + 1) & 3][0], xr[(kc + 1) & 3][1]);
        BARRIER();
#pragma unroll
        for (int ks = 0; ks < 2; ++ks)
#pragma unroll
            for (int j = 0; j < 2; ++j) {
                bc[j][ks] = bn[j][ks];
                if (kc + 2 < 16) bn[j][ks] = nw[j][ks];
            }
    }

    if (w < 4) {
        unsigned short* dst = (w < 2) ? qo : ko;
#pragma unroll
        for (int j = 0; j < 2; ++j) {
            const int nf = (nt0 + j) & 3;
#pragma unroll
            for (int r = 0; r < 4; ++r)
                dst[(size_t)(t0 + 4 * g + r) * HH + 16 * nf + l15] =
                    f2bf(acc[j][r]);
        }
    } else {
        const int b = t0 >> 11, tl = t0 & (TT - 1);
#pragma unroll
        for (int j = 0; j < 2; ++j) {
            const int nf = nt0 + j - 8;
#pragma unroll
            for (int r = 0; r < 4; ++r)
                vo[((size_t)b * HH + 16 * nf + 4 * g + r) * TT + tl + l15] =
                    f2bf(acc[j][r]);
        }
    }
}

// ---------------------------------------------------------------------------
// Kernel 2: causal flash attention, PAIRED q-tiles for perfect balance.
// 256 blocks (= 1/CU, one round) x 8 waves. Block (b,j) runs qt=127-j then
// qt=j as two sequential phases (LDS merge between, reused). Waves split
// each phase's 64-key chunks strided. Swapped QK^T keeps softmax in
// registers; PV reuses P register layout (kappa trick); base-2 softmax.
// ---------------------------------------------------------------------------
__global__ __launch_bounds__(512, 2) void attn_kernel(
    const unsigned short* __restrict__ qw,
    const unsigned short* __restrict__ kw,
    const unsigned short* __restrict__ vw,
    float* __restrict__ out)
{
    __shared__ float om[8][16];
    __shared__ float olg[8][4][16];
    __shared__ __align__(16) float oo[8][16][64];

    const int idx = blockIdx.x;
    const int b = idx & (BB - 1);
    const int j = idx >> 2;                       // 0..63
    const int tid = threadIdx.x;
    const int w = tid >> 6;
    const int lane = tid & 63;
    const int l15 = lane & 15;
    const int g = lane >> 4;

    const unsigned short* kb = kw + (size_t)b * TT * HH;
    const unsigned short* vb = vw + (size_t)b * HH * TT;

    for (int ph = 0; ph < 2; ++ph) {
        const int qt = ph ? j : (TT / 16 - 1) - j;
        const int q0 = qt << 4;
        const int q = q0 + l15;

        const unsigned short* qrow = qw + (size_t)(b * TT + q) * HH + 8 * g;
        ushort8 qf0 = *(const ushort8*)qrow;
        ushort8 qf1 = *(const ushort8*)(qrow + 32);

        float m_run = -3.0e38f, l_run = 0.0f;
        float4v o[4];
#pragma unroll
        for (int i = 0; i < 4; ++i) o[i] = (float4v)0.0f;

        for (int kv0 = 64 * w; kv0 < q0 + 16; kv0 += 512) {
            const unsigned short* kr = kb + (size_t)(kv0 + l15) * HH + 8 * g;
            ushort8 akl[4], akh[4];
#pragma unroll
            for (int f = 0; f < 4; ++f) {
                akl[f] = *(const ushort8*)(kr + f * 16 * HH);
                akh[f] = *(const ushort8*)(kr + f * 16 * HH + 32);
            }
            ushort8 av[4][2];             // V^T kappa-packed, issued early
#pragma unroll
            for (int ht = 0; ht < 4; ++ht) {
                const unsigned short* vp =
                    vb + (size_t)(16 * ht + l15) * TT + kv0 + 4 * g;
#pragma unroll
                for (int g2 = 0; g2 < 2; ++g2) {
                    ushort4v v0 = *(const ushort4v*)(vp + 32 * g2);
                    ushort4v v1 = *(const ushort4v*)(vp + 32 * g2 + 16);
#pragma unroll
                    for (int r = 0; r < 4; ++r) {
                        av[ht][g2][r] = v0[r];
                        av[ht][g2][4 + r] = v1[r];
                    }
                }
            }

            float4v s[4];  // S^T: lane=q, key = kv0 + 16f + 4g + r
#pragma unroll
            for (int f = 0; f < 4; ++f) {
                s[f] = mfma16(akl[f], qf0, (float4v)0.0f);
                s[f] = mfma16(akh[f], qf1, s[f]);
            }

            if (kv0 + 63 > q0) {  // causal mask on boundary chunks
#pragma unroll
                for (int f = 0; f < 4; ++f)
#pragma unroll
                    for (int r = 0; r < 4; ++r)
                        if (kv0 + 16 * f + 4 * g + r > q) s[f][r] = -1e30f;
            }

            float mt = s[0][0];
#pragma unroll
            for (int f = 0; f < 4; ++f)
#pragma unroll
                for (int r = 0; r < 4; ++r) mt = fmaxf(mt, s[f][r]);
            mt = fmaxf(mt, __shfl_xor(mt, 16, 64));
            mt = fmaxf(mt, __shfl_xor(mt, 32, 64));

            const float m_new = fmaxf(m_run, mt);
            const float scale = exp2f(m_run - m_new);
            float sum = 0.0f;             // per-lane partial (merged in LDS)
#pragma unroll
            for (int f = 0; f < 4; ++f)
#pragma unroll
                for (int r = 0; r < 4; ++r) {
                    s[f][r] = exp2f(s[f][r] - m_new);
                    sum += s[f][r];
                }
            l_run = l_run * scale + sum;
            m_run = m_new;
#pragma unroll
            for (int i = 0; i < 4; ++i) o[i] *= scale;

            ushort8 bp[2];                // kappa(g,j) per 32-key group
#pragma unroll
            for (int r = 0; r < 4; ++r) {
                bp[0][r] = f2bf(s[0][r]); bp[0][4 + r] = f2bf(s[1][r]);
                bp[1][r] = f2bf(s[2][r]); bp[1][4 + r] = f2bf(s[3][r]);
            }
#pragma unroll
            for (int ht = 0; ht < 4; ++ht) {
                o[ht] = mfma16(av[ht][0], bp[0], o[ht]);
                o[ht] = mfma16(av[ht][1], bp[1], o[ht]);
            }
        }

        if (lane < 16) om[w][lane] = m_run;
        olg[w][g][l15] = l_run;
#pragma unroll
        for (int ht = 0; ht < 4; ++ht)
            *(float4v*)&oo[w][l15][16 * ht + 4 * g] = o[ht];
        __syncthreads();

#pragma unroll 2
        for (int e = tid; e < 16 * HH; e += 512) {
            const int qq = e >> 6, h = e & 63;
            float mstar = om[0][qq];
#pragma unroll
            for (int w2 = 1; w2 < 8; ++w2) mstar = fmaxf(mstar, om[w2][qq]);
            float lsum = 0.0f, osum = 0.0f;
#pragma unroll
            for (int w2 = 0; w2 < 8; ++w2) {
                const float al = exp2f(om[w2][qq] - mstar);
                const float lw = olg[w2][0][qq] + olg[w2][1][qq] +
                                 olg[w2][2][qq] + olg[w2][3][qq];
                lsum += al * lw;
                osum += al * oo[w2][qq][h];
            }
            out[((size_t)b * TT + q0 + qq) * HH + h] = osum / lsum;
        }
        __syncthreads();   // LDS reused by next phase
    }
}

extern "C" void kernel_launch(void* const* d_in, const int* in_sizes, int n_in,
                              void* d_out, int out_size, void* d_ws, size_t ws_size,
                              hipStream_t stream) {
    // setup_inputs order: x, Wk, Wq, Wv
    const float* x  = (const float*)d_in[0];
    const float* Wk = (const float*)d_in[1];
    const float* Wq = (const float*)d_in[2];
    const float* Wv = (const float*)d_in[3];

    // ws: q bf16 [B*T][64] | k bf16 [B*T][64] | vT bf16 [B][64][T] | wf 384KB
    unsigned short* q_ws  = (unsigned short*)d_ws;
    unsigned short* k_ws  = q_ws + (size_t)BB * TT * HH;
    unsigned short* vt_ws = k_ws + (size_t)BB * TT * HH;
    unsigned short* wf_ws = vt_ws + (size_t)BB * TT * HH;

    wconv_kernel<<<96, 256, 0, stream>>>(Wq, Wk, Wv, wf_ws);
    proj_kernel<<<BB * TT / 16, 384, 0, stream>>>(x, wf_ws, q_ws, k_ws, vt_ws);
    attn_kernel<<<BB * TT / 32, 512, 0, stream>>>(q_ws, k_ws, vt_ws, (float*)d_out);
}